// Round 16
// baseline (280.036 us; speedup 1.0000x reference)
//
#include <hip/hip_runtime.h>

typedef unsigned int uint32;
typedef unsigned short u16;
typedef float fx4 __attribute__((ext_vector_type(4)));
typedef uint32 u32x4 __attribute__((ext_vector_type(4)));

typedef const __attribute__((address_space(1))) void gvoid;
typedef __attribute__((address_space(3))) void lvoid;

#define MFMA_BF16_16x16x32(acc, a, b) \
  asm("v_mfma_f32_16x16x32_bf16 %0, %1, %2, %0" : "+v"(acc) : "v"(a), "v"(b))

#define WAIT_LGKM0() asm volatile("s_waitcnt lgkmcnt(0)" ::: "memory")
#define WAIT_LGKM4() asm volatile("s_waitcnt lgkmcnt(4)" ::: "memory")
#define WAIT_VM0()   asm volatile("s_waitcnt vmcnt(0)" ::: "memory")
#define WAIT_VM3()   asm volatile("s_waitcnt vmcnt(3)" ::: "memory")
#define WAIT_VM6()   asm volatile("s_waitcnt vmcnt(6)" ::: "memory")
#define SFENCE()     __builtin_amdgcn_sched_barrier(0)
#define BARRIER()    do { __builtin_amdgcn_s_barrier(); asm volatile("" ::: "memory"); } while (0)
#define NOWAIT()     do { } while (0)

__device__ __forceinline__ u16 f2bf_rne(float f) {
  uint32 u = __builtin_bit_cast(uint32, f);
  u += 0x7FFFu + ((u >> 16) & 1u);
  return (u16)(u >> 16);
}

// ---------------------------------------------------------------------------
// x (fp32) -> bf16
// ---------------------------------------------------------------------------
__global__ __launch_bounds__(256) void cvtx_kernel(const float* __restrict__ x,
                                                   u16* __restrict__ xb) {
  const int i = blockIdx.x * 256 + threadIdx.x;
  float4 v = ((const float4*)x)[i];
  ushort4 o;
  o.x = f2bf_rne(v.x);
  o.y = f2bf_rne(v.y);
  o.z = f2bf_rne(v.z);
  o.w = f2bf_rne(v.w);
  ((ushort4*)xb)[i] = o;
}

// ---------------------------------------------------------------------------
// decode (r13-verified): dec[t,r,d] = scales[t]*0.25 * sum_k cw[idx[t,r,k],d]
// ---------------------------------------------------------------------------
__global__ __launch_bounds__(256) void decode_kernel(
    const float* __restrict__ cw, const int* __restrict__ indices,
    const float* __restrict__ scales, u16* __restrict__ dec) {
  const int row = blockIdx.x;      // t*512 + r
  const int t = row >> 9;
  const int* ip = indices + (size_t)row * 4;
  const float* c0 = cw + (size_t)ip[0] * 4096;
  const float* c1 = cw + (size_t)ip[1] * 4096;
  const float* c2 = cw + (size_t)ip[2] * 4096;
  const float* c3 = cw + (size_t)ip[3] * 4096;
  const float s = scales[t] * 0.25f;
  u16* orow = dec + (size_t)row * 4096;
  const int tid = threadIdx.x;
#pragma unroll
  for (int j = 0; j < 4; ++j) {
    const int d = j * 1024 + tid * 4;
    float4 a = *(const float4*)(c0 + d);
    float4 b = *(const float4*)(c1 + d);
    float4 c = *(const float4*)(c2 + d);
    float4 e = *(const float4*)(c3 + d);
    ushort4 o;
    o.x = f2bf_rne((a.x + b.x + c.x + e.x) * s);
    o.y = f2bf_rne((a.y + b.y + c.y + e.y) * s);
    o.z = f2bf_rne((a.z + b.z + c.z + e.z) * s);
    o.w = f2bf_rne((a.w + b.w + c.w + e.w) * s);
    *(ushort4*)(orow + d) = o;
  }
}

// ---------------------------------------------------------------------------
// gemm_z: z[t] = x_bf16 @ rot[t]^T.  256x256 tile, BK=32, 8 waves (2x4),
// wave tile 128x64, acc[8][4]. LDS 144KB: A 3 bufs x [256][32]bf16,
// B 3 bufs x [256][32]fp32 -- BOTH staged via global_load_lds with
// pre-swizzled sources (no pack, no ds_writes). fp32 B converted to bf16
// at frag-read time with v_perm truncation (r1-verified numerics).
// TRIPLE buffering => stage(kt+2) never touches a buffer being read =>
// per K-tile: 16 ds_reads (pinned order) -> 6 stage-issues -> lgkm(4) ->
// perms + 16 MFMA -> lgkm(0) -> 16 MFMA -> vm6 -> ONE barrier.
// FIFO audit: tail vm6 retires stage(kt+1) exactly; stage(kt+2) keeps
// ~2 iters (~1200cyc) of HBM cover. 126=3*42 uniform triples; iter 126
// drains vm0; iter 127 compute-only.
// ---------------------------------------------------------------------------
__global__ __launch_bounds__(512, 2) void gemm_z_kernel(
    const u16* __restrict__ Xb,    // [512][4096] bf16
    const float* __restrict__ rot, // [8][4096][4096] fp32
    u16* __restrict__ Z) {         // [8][512][4096] bf16
  __shared__ char sA[49152];       // 3 x 16KB
  __shared__ char sB[98304];       // 3 x 32KB

  const int lb = blockIdx.x;
  const int swz = ((lb & 7) << 5) | (lb >> 3);   // XCD-chunked, 256%8==0
  const int t = swz >> 5;
  const int rem = swz & 31;
  const int nb = rem >> 1, mb = rem & 1;
  const float* Bt = rot + ((size_t)t << 24);
  u16* Ct = Z + ((size_t)t << 21);
  const int aRow0 = mb << 8, bCol0 = nb << 8;
  const int tid = threadIdx.x;
  const int wv = tid >> 6, ln = tid & 63;
  const int lr = ln & 15, lk = ln >> 4;
  const int wr = wv >> 2, wc = wv & 3;

  fx4 acc[8][4] = {};

  // A: [256 rows][4 chunks of 16B]; source chunk pre-swizzle key (row>>1)&3
  const u16* Asrc = Xb + (size_t)(aRow0 + (tid >> 2)) * 4096 +
                    (((tid & 3) ^ ((tid >> 3) & 3)) << 3);
  // B: [256 rows][8 chunks of 16B] fp32; source chunk pre-swizzle key row&7
  const float* Bsrc = Bt + (size_t)(bCol0 + (tid >> 3)) * 4096 +
                      (((tid & 7) ^ ((tid >> 3) & 7)) << 2);
  // frag read constants
  const int gr = (lr >> 1) & 3;
  const int aof = (wr * 128 + lr) * 64 + ((lk ^ gr) << 4);  // + m*1024
  const int brx = lr & 7;
  const int c0 = ((2 * lk) ^ brx) << 4;                     // c1 = c0 ^ 16
  const int bof = (wc * 64 + lr) * 128;                     // + n*2048

#define STAGE_A2(DB, KT)                                                      \
  _Pragma("unroll")                                                           \
  for (int c = 0; c < 2; ++c)                                                 \
    __builtin_amdgcn_global_load_lds(                                         \
        (gvoid*)(Asrc + (size_t)(c * 128) * 4096 + (KT) * 32),                \
        (lvoid*)(sA + (DB) * 16384 + c * 8192 + tid * 16), 16, 0, 0)

#define STAGE_B4(DB, KT)                                                      \
  _Pragma("unroll")                                                           \
  for (int c = 0; c < 4; ++c)                                                 \
    __builtin_amdgcn_global_load_lds(                                         \
        (gvoid*)(Bsrc + (size_t)(c * 64) * 4096 + (KT) * 32),                 \
        (lvoid*)(sB + (DB) * 32768 + c * 8192 + tid * 16), 16, 0, 0)

#define MFMA_HALF(MB)                                                         \
  do {                                                                        \
    __builtin_amdgcn_s_setprio(1);                                            \
    _Pragma("unroll")                                                         \
    for (int m = 0; m < 4; ++m)                                               \
      _Pragma("unroll")                                                       \
      for (int n = 0; n < 4; ++n)                                             \
        MFMA_BF16_16x16x32(acc[(MB) + m][n], af[(MB) + m], bf[n]);            \
    __builtin_amdgcn_s_setprio(0);                                            \
  } while (0)

// One K-tile. D = read buf, SD = stage dest buf ((D+2)%3), KT = k index.
#define ITER_Z(D, SD, KT, DOSTAGE, TAILW)                                     \
  do {                                                                        \
    const char* pA_ = sA + (D) * 16384;                                       \
    const char* pB_ = sB + (D) * 32768;                                       \
    af[0] = *(const u32x4*)(pA_ + aof);                                       \
    af[1] = *(const u32x4*)(pA_ + aof + 1024);                                \
    af[2] = *(const u32x4*)(pA_ + aof + 2048);                                \
    af[3] = *(const u32x4*)(pA_ + aof + 3072);                                \
    SFENCE();                                                                 \
    ub[0][0] = *(const u32x4*)(pB_ + bof + c0);                               \
    ub[0][1] = *(const u32x4*)(pB_ + bof + (c0 ^ 16));                        \
    ub[1][0] = *(const u32x4*)(pB_ + bof + 2048 + c0);                        \
    ub[1][1] = *(const u32x4*)(pB_ + bof + 2048 + (c0 ^ 16));                 \
    ub[2][0] = *(const u32x4*)(pB_ + bof + 4096 + c0);                        \
    ub[2][1] = *(const u32x4*)(pB_ + bof + 4096 + (c0 ^ 16));                 \
    ub[3][0] = *(const u32x4*)(pB_ + bof + 6144 + c0);                        \
    ub[3][1] = *(const u32x4*)(pB_ + bof + 6144 + (c0 ^ 16));                 \
    SFENCE();                                                                 \
    af[4] = *(const u32x4*)(pA_ + aof + 4096);                                \
    af[5] = *(const u32x4*)(pA_ + aof + 5120);                                \
    af[6] = *(const u32x4*)(pA_ + aof + 6144);                                \
    af[7] = *(const u32x4*)(pA_ + aof + 7168);                                \
    SFENCE();                                                                 \
    if (DOSTAGE) {                                                            \
      STAGE_A2(SD, (KT) + 2);                                                 \
      STAGE_B4(SD, (KT) + 2);                                                 \
    }                                                                         \
    SFENCE();                                                                 \
    WAIT_LGKM4();                /* af[0..3] + all B retired */               \
    SFENCE();                                                                 \
    _Pragma("unroll")                                                         \
    for (int n = 0; n < 4; ++n) {                                             \
      bf[n][0] = __builtin_amdgcn_perm(ub[n][0][1], ub[n][0][0], 0x07060302u);\
      bf[n][1] = __builtin_amdgcn_perm(ub[n][0][3], ub[n][0][2], 0x07060302u);\
      bf[n][2] = __builtin_amdgcn_perm(ub[n][1][1], ub[n][1][0], 0x07060302u);\
      bf[n][3] = __builtin_amdgcn_perm(ub[n][1][3], ub[n][1][2], 0x07060302u);\
    }                                                                         \
    MFMA_HALF(0);                                                             \
    WAIT_LGKM0();                                                             \
    SFENCE();                                                                 \
    MFMA_HALF(4);                                                             \
    TAILW;                                                                    \
    BARRIER();                                                                \
  } while (0)

  u32x4 af[8], bf[4], ub[4][2];

  // ---- prologue: stage(0)->buf0, stage(1)->buf1; vm6 retires stage(0) ----
  STAGE_A2(0, 0);
  STAGE_B4(0, 0);
  SFENCE();
  STAGE_A2(1, 1);
  STAGE_B4(1, 1);
  SFENCE();
  WAIT_VM6();
  BARRIER();

  // ---- steady: 42 uniform triples (kt = 0..125), stage kt+2 ----
#pragma unroll 1
  for (int kt = 0; kt < 126; kt += 3) {
    ITER_Z(0, 2, kt, 1, WAIT_VM6());
    ITER_Z(1, 0, kt + 1, 1, WAIT_VM6());
    ITER_Z(2, 1, kt + 2, 1, WAIT_VM6());
  }
  // kt = 126 (buf 0): no stage; drain stage(127) before reading buf 1
  ITER_Z(0, 0, 126, 0, WAIT_VM0());
  // kt = 127 (buf 1): compute only
  ITER_Z(1, 0, 127, 0, NOWAIT());

  // C/D layout: col = lane&15, row = (lane>>4)*4 + j
#pragma unroll
  for (int m = 0; m < 8; ++m) {
    const int r0 = aRow0 + wr * 128 + m * 16 + lk * 4;
#pragma unroll
    for (int n = 0; n < 4; ++n) {
      const int col = bCol0 + wc * 64 + n * 16 + lr;
#pragma unroll
      for (int j = 0; j < 4; ++j)
        Ct[(size_t)(r0 + j) * 4096 + col] = f2bf_rne(acc[m][n][j]);
    }
  }
#undef STAGE_A2
#undef STAGE_B4
#undef MFMA_HALF
#undef ITER_Z
}

// ---------------------------------------------------------------------------
// gemm_out (r10/r15-verified): out = z@dec^T + bias. 128x64 tile, BK=32,
// 128 K-steps, quad-buffered depth-3 counted-vmcnt pipeline.
// ---------------------------------------------------------------------------
__global__ __launch_bounds__(256, 2) void gemm_out_kernel(
    const u16* __restrict__ Z,    // [8][512][4096]
    const u16* __restrict__ Dec,  // [8][512][4096]
    const float* __restrict__ bias,
    float* __restrict__ out) {    // [512][4096]
  __shared__ char sm[49152];      // 4 bufs x (A 8KB + B 4KB)
  const int lb = blockIdx.x;
  const int swz = ((lb & 7) << 5) | (lb >> 3);  // 256 % 8 == 0
  const int t = swz >> 5;
  const int rem = swz & 31;
  const int nb = rem >> 2, mb = rem & 3;
  const u16* At = Z + ((size_t)t << 21);
  const u16* Bt = Dec + ((size_t)t << 21);
  const int aRow0 = mb << 7, bCol0 = nb << 6;
  const int tid = threadIdx.x;
  const int wv = tid >> 6, ln = tid & 63;
  const int lr = ln & 15, lk = ln >> 4;
  const int wr = wv >> 1, wc = wv & 1;

  fx4 acc[4][2] = {};

  const int kswz = (((tid & 3) ^ ((tid >> 3) & 3)) << 3);
  const u16* Asrc = At + (size_t)(aRow0 + (tid >> 2)) * 4096 + kswz;
  const u16* Bsrc = Bt + (size_t)(bCol0 + (tid >> 2)) * 4096 + kswz;
  const int gr = (lr >> 1) & 3;
  const int aof = (wr * 64 + lr) * 64 + ((lk ^ gr) << 4);          // + m*1024
  const int bof = 8192 + (wc * 32 + lr) * 64 + ((lk ^ gr) << 4);   // + n*1024

#define STAGE_O(buf, kofs)                                                   \
  do {                                                                       \
    _Pragma("unroll")                                                        \
    for (int c = 0; c < 2; ++c)                                              \
      __builtin_amdgcn_global_load_lds(                                      \
          (gvoid*)(Asrc + (size_t)(c << 6) * 4096 + (kofs)),                 \
          (lvoid*)((buf) + c * 4096 + tid * 16), 16, 0, 0);                  \
    __builtin_amdgcn_global_load_lds((gvoid*)(Bsrc + (kofs)),                \
                                     (lvoid*)((buf) + 8192 + tid * 16), 16,  \
                                     0, 0);                                  \
  } while (0)

  char* b0 = sm;
  char* b1 = sm + 12288;
  char* b2 = sm + 24576;
  char* b3 = sm + 36864;
  STAGE_O(b0, 0);
  STAGE_O(b1, 32);
  STAGE_O(b2, 64);
  WAIT_VM6();                     // stage(0) complete; 1,2 in flight
  BARRIER();

#pragma unroll 1
  for (int kt = 0; kt < 128; ++kt) {
    if (kt + 3 < 128) STAGE_O(b3, (kt + 3) << 5);
    u32x4 af[4], bf[2];
#pragma unroll
    for (int m = 0; m < 4; ++m)
      af[m] = *(const u32x4*)(b0 + aof + m * 1024);
#pragma unroll
    for (int n = 0; n < 2; ++n)
      bf[n] = *(const u32x4*)(b0 + bof + n * 1024);
    WAIT_LGKM0();
    SFENCE();
#pragma unroll
    for (int m = 0; m < 4; ++m)
#pragma unroll
      for (int n = 0; n < 2; ++n)
        MFMA_BF16_16x16x32(acc[m][n], af[m], bf[n]);
    if (kt + 3 < 128) {
      WAIT_VM6();                 // stage(kt+1) done; kt+2, kt+3 in flight
    } else if (kt + 2 < 128) {
      WAIT_VM3();                 // kt = 125
    } else {
      WAIT_VM0();                 // kt = 126, 127
    }
    BARRIER();
    char* tmp = b0; b0 = b1; b1 = b2; b2 = b3; b3 = tmp;
  }

#pragma unroll
  for (int n = 0; n < 2; ++n) {
    const int colg = (t << 9) + bCol0 + wc * 32 + n * 16 + lr;
    const float bv = bias[colg];
#pragma unroll
    for (int m = 0; m < 4; ++m) {
      const int r0 = aRow0 + wr * 64 + m * 16 + lk * 4;
#pragma unroll
      for (int j = 0; j < 4; ++j)
        out[(size_t)(r0 + j) * 4096 + colg] = acc[m][n][j] + bv;
    }
  }
#undef STAGE_O
}

// ---------------------------------------------------------------------------
extern "C" void kernel_launch(void* const* d_in, const int* in_sizes, int n_in,
                              void* d_out, int out_size, void* d_ws, size_t ws_size,
                              hipStream_t stream) {
  const float* x       = (const float*)d_in[0];   // [512][4096]
  const float* cw      = (const float*)d_in[1];   // [16384][4096]
  const int*   indices = (const int*)d_in[2];     // [8][512][4]
  const float* rot     = (const float*)d_in[3];   // [8][4096][4096]
  const float* scales  = (const float*)d_in[4];   // [8]
  const float* bias    = (const float*)d_in[5];   // [4096]
  float* out = (float*)d_out;
  char* ws = (char*)d_ws;

  u16* xb  = (u16*)(ws);                          // 4 MiB
  u16* dec = (u16*)(ws + ((size_t)4 << 20));      // 32 MiB
  u16* z   = (u16*)(ws + ((size_t)36 << 20));     // 32 MiB

  decode_kernel<<<dim3(4096), dim3(256), 0, stream>>>(cw, indices, scales, dec);
  cvtx_kernel<<<dim3(2048), dim3(256), 0, stream>>>(x, xb);
  gemm_z_kernel<<<dim3(256), dim3(512), 0, stream>>>(xb, rot, z);
  gemm_out_kernel<<<dim3(256), dim3(256), 0, stream>>>(z, dec, bias, out);
}